// Round 3
// baseline (88.816 us; speedup 1.0000x reference)
//
#include <hip/hip_runtime.h>

#define NTHREADS 256
#define N_ATOMS 1024
#define HIDDEN 64

// One block per QUAD of atoms (grid = B*N/4 = 2048), 256 threads.
// Round-5 change vs round-4 (2-atom): 4-atom batching. The wave-0 MLP tail
// loads each weight ONCE per 4 atoms (per-atom tail 345 -> ~260 wave-insts;
// weight L1/L2 traffic halved 170 -> 85 MB). Phase 1a runs as two
// register-reusing passes (atoms 0/1 then 2/3), each with one packed
// atomicAdd. All per-atom state is interleaved [k][atom] so the tail does
// 1 weight load + 1 ds_read_b128 + 4 fma per k. LDS ~36.6 KB -> 4 blocks/CU
// (16 waves/CU), grid needs 2 residency rounds.
__global__ __launch_bounds__(NTHREADS) void LocalFeatureEncoder_40063454937486_kernel(
    const float* __restrict__ pos,    // [B,N,3]
    const int*   __restrict__ types,  // [B,N]
    const float* __restrict__ W1,     // [34,64]
    const float* __restrict__ b1,     // [64]
    const float* __restrict__ W2,     // [64,64]
    const float* __restrict__ b2,     // [64]
    const float* __restrict__ W3,     // [64,64]
    const float* __restrict__ b3,     // [64]
    float*       __restrict__ out)    // [B,N,64]
{
    const int blk  = blockIdx.x;          // bidx*256 + quad
    const int bidx = blk >> 8;            // 256 quads per batch
    const int i0   = (blk & 255) * 4;
    const int tid  = threadIdx.x;
    const int lane = tid & 63;
    const int wav  = tid >> 6;

    __shared__ __align__(16) float qd[4][N_ATOMS];   // queue: distance
    __shared__ __align__(16) float qm[4][N_ATOMS];   // queue: +cutv type0 / -cutv type1
    __shared__ __align__(16) float partial[4 * 128]; // [wav][f=2r+s][atom]
    __shared__ __align__(16) float feats[34 * 4];    // [k][atom]
    __shared__ __align__(16) float h1s[HIDDEN * 4];  // [k][atom]
    __shared__ __align__(16) float h2s[HIDDEN * 4];  // [k][atom]
    __shared__ int cnt01;                             // packed: n0 | n1<<16
    __shared__ int cnt23;                             // packed: n2 | n3<<16

    const float* pf   = pos + (size_t)bidx * (N_ATOMS * 3);
    const int*   typb = types + (size_t)bidx * N_ATOMS;

    // ---- issue all neighbor loads BEFORE the barrier (latency overlap) ----
    const float4 p0 = *(const float4*)(pf + tid * 12);
    const float4 p1 = *(const float4*)(pf + tid * 12 + 4);
    const float4 p2 = *(const float4*)(pf + tid * 12 + 8);
    const int4   tv = *(const int4*)(typb + tid * 4);

    float xi[4], yi[4], zi[4];
#pragma unroll
    for (int a = 0; a < 4; ++a) {
        xi[a] = pf[(i0 + a) * 3 + 0];
        yi[a] = pf[(i0 + a) * 3 + 1];
        zi[a] = pf[(i0 + a) * 3 + 2];
    }

    if (tid == 0) { cnt01 = 0; cnt23 = 0; }
    __syncthreads();                      // counters = 0 visible

    // ---------- phase 1a: distances + compaction, two 2-atom passes ----------
    {
        const float px[4] = {p0.x, p0.w, p1.z, p2.y};
        const float py[4] = {p0.y, p1.x, p1.w, p2.z};
        const float pz[4] = {p0.z, p1.y, p2.x, p2.w};
        const int   tj[4] = {tv.x, tv.y, tv.z, tv.w};
        const unsigned long long lt = (1ull << lane) - 1ull;

#pragma unroll
        for (int pass = 0; pass < 2; ++pass) {
            const int aA = pass * 2, aB = pass * 2 + 1;
            const int iA = i0 + aA,  iB = i0 + aB;
            int* cptr = pass ? &cnt23 : &cnt01;

            float sqA[4], sqB[4];
            bool  prA[4], prB[4];
            unsigned long long mA[4], mB[4];
#pragma unroll
            for (int q = 0; q < 4; ++q) {
                const int j = tid * 4 + q;
                float dx = xi[aA] - px[q], dy = yi[aA] - py[q], dz = zi[aA] - pz[q];
                sqA[q] = dx * dx + dy * dy + dz * dz;
                dx = xi[aB] - px[q]; dy = yi[aB] - py[q]; dz = zi[aB] - pz[q];
                sqB[q] = dx * dx + dy * dy + dz * dz;
                prA[q] = (j != iA) && (sqA[q] < 6.25f);
                prB[q] = (j != iB) && (sqB[q] < 6.25f);
                mA[q]  = __ballot(prA[q]);
                mB[q]  = __ballot(prB[q]);
            }

            const int totA = (int)(__popcll(mA[0]) + __popcll(mA[1]) +
                                   __popcll(mA[2]) + __popcll(mA[3]));
            const int totB = (int)(__popcll(mB[0]) + __popcll(mB[1]) +
                                   __popcll(mB[2]) + __popcll(mB[3]));
            int basep = 0;
            if (lane == 0) basep = atomicAdd(cptr, totA | (totB << 16));
            basep = __shfl(basep, 0, 64);     // convergent broadcast

            int offA = basep & 0xffff;
            int offB = (basep >> 16) & 0xffff;
#pragma unroll
            for (int q = 0; q < 4; ++q) {
                if (prA[q]) {
                    const float d  = sqrtf(sqA[q]);
                    const float x  = d * 0.4f;    // d / 2.5
                    const float x3 = x * x * x;
                    const float cutv = 1.0f + x3 * (-10.0f + x * (15.0f - 6.0f * x));
                    const int idx = offA + (int)__popcll(mA[q] & lt);
                    qd[aA][idx] = d;
                    qm[aA][idx] = (tj[q] == 0) ? cutv : -cutv;
                }
                if (prB[q]) {
                    const float d  = sqrtf(sqB[q]);
                    const float x  = d * 0.4f;
                    const float x3 = x * x * x;
                    const float cutv = 1.0f + x3 * (-10.0f + x * (15.0f - 6.0f * x));
                    const int idx = offB + (int)__popcll(mB[q] & lt);
                    qd[aB][idx] = d;
                    qm[aB][idx] = (tj[q] == 0) ? cutv : -cutv;
                }
                offA += (int)__popcll(mA[q]); // wave-uniform prefix
                offB += (int)__popcll(mB[q]);
            }
        }
    }
    __syncthreads();
    int n[4];
    {
        const int pk01 = cnt01, pk23 = cnt23;
        n[0] = pk01 & 0xffff;  n[1] = (pk01 >> 16) & 0xffff;
        n[2] = pk23 & 0xffff;  n[3] = (pk23 >> 16) & 0xffff;
    }
    int nmax = n[0];
    if (n[1] > nmax) nmax = n[1];
    if (n[2] > nmax) nmax = n[2];
    if (n[3] > nmax) nmax = n[3];

    // ---------- phase 1b: r-parallel RBF accumulation, 4 atoms ----------
    {
        const int slot = tid >> 4;            // pair slot 0..15
        const int r    = tid & 15;            // RBF center 0..15
        const float c  = (float)r * (2.5f / 15.0f);

        float a0[4] = {0.f, 0.f, 0.f, 0.f};   // species0, atoms 0..3
        float a1[4] = {0.f, 0.f, 0.f, 0.f};   // species1, atoms 0..3
        for (int e = slot; e < nmax; e += 16) {
#pragma unroll
            for (int a = 0; a < 4; ++a) {
                if (e < n[a]) {
                    const float d    = qd[a][e];
                    const float mm   = qm[a][e];
                    const float diff = d - c;
                    const float ex   = __expf(-(diff * diff) * 36.0f);
                    a0[a] = fmaf(fmaxf( mm, 0.0f), ex, a0[a]);
                    a1[a] = fmaf(fmaxf(-mm, 0.0f), ex, a1[a]);
                }
            }
        }
#pragma unroll
        for (int a = 0; a < 4; ++a) {
            a0[a] += __shfl_xor(a0[a], 16, 64);  a0[a] += __shfl_xor(a0[a], 32, 64);
            a1[a] += __shfl_xor(a1[a], 16, 64);  a1[a] += __shfl_xor(a1[a], 32, 64);
        }
        if (lane < 16) {
            // partial[wav][f][atom], f=2r+s -> two float4 per lane
            const float4 v0 = {a0[0], a0[1], a0[2], a0[3]};   // f = 2r
            const float4 v1 = {a1[0], a1[1], a1[2], a1[3]};   // f = 2r+1
            *(float4*)&partial[wav * 128 + r * 8]     = v0;
            *(float4*)&partial[wav * 128 + r * 8 + 4] = v1;
        }
        if (tid == 0) {
#pragma unroll
            for (int a = 0; a < 4; ++a) {
                const int t = typb[i0 + a];
                feats[a]     = (t == 0) ? 1.0f : 0.0f;   // k=0 (species0)
                feats[4 + a] = (t == 1) ? 1.0f : 0.0f;   // k=1 (species1)
            }
        }
    }
    __syncthreads();

    // ---------- wave-0-only tail: finalize feats + 3-layer MLP, 4 atoms ----------
    if (tid < HIDDEN) {
        if (tid < 32) {
            float4 acc      = *(const float4*)&partial[tid * 4];
            const float4 q1 = *(const float4*)&partial[128 + tid * 4];
            const float4 q2 = *(const float4*)&partial[256 + tid * 4];
            const float4 q3 = *(const float4*)&partial[384 + tid * 4];
            acc.x += q1.x + q2.x + q3.x;
            acc.y += q1.y + q2.y + q3.y;
            acc.z += q1.z + q2.z + q3.z;
            acc.w += q1.w + q2.w + q3.w;
            *(float4*)&feats[8 + tid * 4] = acc;     // k = 2 + f
        }
        __builtin_amdgcn_wave_barrier();

        float h[4];
        {
            const float bb = b1[tid];
            h[0] = bb; h[1] = bb; h[2] = bb; h[3] = bb;
#pragma unroll
            for (int k = 0; k < 34; ++k) {
                const float w  = W1[k * HIDDEN + tid];
                const float4 f = *(const float4*)&feats[k * 4];
                h[0] = fmaf(f.x, w, h[0]);  h[1] = fmaf(f.y, w, h[1]);
                h[2] = fmaf(f.z, w, h[2]);  h[3] = fmaf(f.w, w, h[3]);
            }
#pragma unroll
            for (int a = 0; a < 4; ++a) h[a] = h[a] / (1.0f + __expf(-h[a]));
            *(float4*)&h1s[tid * 4] = make_float4(h[0], h[1], h[2], h[3]);
        }
        __builtin_amdgcn_wave_barrier();

        {
            const float bb = b2[tid];
            h[0] = bb; h[1] = bb; h[2] = bb; h[3] = bb;
#pragma unroll
            for (int k = 0; k < HIDDEN; ++k) {
                const float w  = W2[k * HIDDEN + tid];
                const float4 f = *(const float4*)&h1s[k * 4];
                h[0] = fmaf(f.x, w, h[0]);  h[1] = fmaf(f.y, w, h[1]);
                h[2] = fmaf(f.z, w, h[2]);  h[3] = fmaf(f.w, w, h[3]);
            }
#pragma unroll
            for (int a = 0; a < 4; ++a) h[a] = h[a] / (1.0f + __expf(-h[a]));
            *(float4*)&h2s[tid * 4] = make_float4(h[0], h[1], h[2], h[3]);
        }
        __builtin_amdgcn_wave_barrier();

        {
            const float bb = b3[tid];
            float o[4] = {bb, bb, bb, bb};
#pragma unroll
            for (int k = 0; k < HIDDEN; ++k) {
                const float w  = W3[k * HIDDEN + tid];
                const float4 f = *(const float4*)&h2s[k * 4];
                o[0] = fmaf(f.x, w, o[0]);  o[1] = fmaf(f.y, w, o[1]);
                o[2] = fmaf(f.z, w, o[2]);  o[3] = fmaf(f.w, w, o[3]);
            }
            const size_t row0 = (size_t)(bidx * N_ATOMS + i0) * HIDDEN;
#pragma unroll
            for (int a = 0; a < 4; ++a)
                out[row0 + (size_t)a * HIDDEN + tid] = o[a];  // contiguous rows
        }
    }
}

extern "C" void kernel_launch(void* const* d_in, const int* in_sizes, int n_in,
                              void* d_out, int out_size, void* d_ws, size_t ws_size,
                              hipStream_t stream) {
    const float* pos   = (const float*)d_in[0];
    const int*   types = (const int*)d_in[1];
    const float* W1    = (const float*)d_in[2];
    const float* b1    = (const float*)d_in[3];
    const float* W2    = (const float*)d_in[4];
    const float* b2    = (const float*)d_in[5];
    const float* W3    = (const float*)d_in[6];
    const float* b3    = (const float*)d_in[7];
    float*       out   = (float*)d_out;

    const int BN = in_sizes[1];           // B*N = 8192
    const int nblocks = BN >> 2;          // one block per atom quad

    LocalFeatureEncoder_40063454937486_kernel<<<nblocks, NTHREADS, 0, stream>>>(
        pos, types, W1, b1, W2, b2, W3, b3, out);
}

// Round 4
// 85.495 us; speedup vs baseline: 1.0388x; 1.0388x over previous
//
#include <hip/hip_runtime.h>

#define NTHREADS 256
#define N_ATOMS 1024
#define HIDDEN 64
#define QCAP 256   // neighbor-queue capacity per atom; mean n~67, sigma~8 ->
                   // 256 is >20 sigma. Stores are bounds-guarded; overflow
                   // would truncate (and fail absmax), never corrupt LDS.

// One block per QUAD of atoms (grid = B*N/4 = 2048), 256 threads.
// Round-6 = round-5 (4-atom batching) with CAPPED neighbor queues.
// Round-5 regressed (83.6 -> 88.8) because full-size queues cost 32 KB LDS
// -> 36.6 KB/block -> 4 blocks/CU: head TLP halved and the wave-0-only tail
// ran with only 4 waves/CU while finished blocks pinned their LDS.
// With QCAP=256 the block needs ~12.8 KB -> 8 blocks/CU (wave-capped),
// grid 2048 = ONE residency round, 8 overlapping tails per CU, while
// keeping round-5's tail amortization (1 weight load + 1 ds_read_b128 +
// 4 fma per k for 4 atoms).
__global__ __launch_bounds__(NTHREADS) void LocalFeatureEncoder_40063454937486_kernel(
    const float* __restrict__ pos,    // [B,N,3]
    const int*   __restrict__ types,  // [B,N]
    const float* __restrict__ W1,     // [34,64]
    const float* __restrict__ b1,     // [64]
    const float* __restrict__ W2,     // [64,64]
    const float* __restrict__ b2,     // [64]
    const float* __restrict__ W3,     // [64,64]
    const float* __restrict__ b3,     // [64]
    float*       __restrict__ out)    // [B,N,64]
{
    const int blk  = blockIdx.x;          // bidx*256 + quad
    const int bidx = blk >> 8;            // 256 quads per batch
    const int i0   = (blk & 255) * 4;
    const int tid  = threadIdx.x;
    const int lane = tid & 63;
    const int wav  = tid >> 6;

    __shared__ __align__(16) float qd[4][QCAP];      // queue: distance
    __shared__ __align__(16) float qm[4][QCAP];      // queue: +cutv t0 / -cutv t1
    __shared__ __align__(16) float partial[4 * 128]; // [wav][f=2r+s][atom]
    __shared__ __align__(16) float feats[34 * 4];    // [k][atom]
    __shared__ __align__(16) float h1s[HIDDEN * 4];  // [k][atom]
    __shared__ __align__(16) float h2s[HIDDEN * 4];  // [k][atom]
    __shared__ int cnt01;                             // packed: n0 | n1<<16
    __shared__ int cnt23;                             // packed: n2 | n3<<16

    const float* pf   = pos + (size_t)bidx * (N_ATOMS * 3);
    const int*   typb = types + (size_t)bidx * N_ATOMS;

    // ---- issue all neighbor loads BEFORE the barrier (latency overlap) ----
    const float4 p0 = *(const float4*)(pf + tid * 12);
    const float4 p1 = *(const float4*)(pf + tid * 12 + 4);
    const float4 p2 = *(const float4*)(pf + tid * 12 + 8);
    const int4   tv = *(const int4*)(typb + tid * 4);

    float xi[4], yi[4], zi[4];
#pragma unroll
    for (int a = 0; a < 4; ++a) {
        xi[a] = pf[(i0 + a) * 3 + 0];
        yi[a] = pf[(i0 + a) * 3 + 1];
        zi[a] = pf[(i0 + a) * 3 + 2];
    }

    if (tid == 0) { cnt01 = 0; cnt23 = 0; }
    __syncthreads();                      // counters = 0 visible

    // ---------- phase 1a: distances + compaction, two 2-atom passes ----------
    {
        const float px[4] = {p0.x, p0.w, p1.z, p2.y};
        const float py[4] = {p0.y, p1.x, p1.w, p2.z};
        const float pz[4] = {p0.z, p1.y, p2.x, p2.w};
        const int   tj[4] = {tv.x, tv.y, tv.z, tv.w};
        const unsigned long long lt = (1ull << lane) - 1ull;

#pragma unroll
        for (int pass = 0; pass < 2; ++pass) {
            const int aA = pass * 2, aB = pass * 2 + 1;
            const int iA = i0 + aA,  iB = i0 + aB;
            int* cptr = pass ? &cnt23 : &cnt01;

            float sqA[4], sqB[4];
            bool  prA[4], prB[4];
            unsigned long long mA[4], mB[4];
#pragma unroll
            for (int q = 0; q < 4; ++q) {
                const int j = tid * 4 + q;
                float dx = xi[aA] - px[q], dy = yi[aA] - py[q], dz = zi[aA] - pz[q];
                sqA[q] = dx * dx + dy * dy + dz * dz;
                dx = xi[aB] - px[q]; dy = yi[aB] - py[q]; dz = zi[aB] - pz[q];
                sqB[q] = dx * dx + dy * dy + dz * dz;
                prA[q] = (j != iA) && (sqA[q] < 6.25f);
                prB[q] = (j != iB) && (sqB[q] < 6.25f);
                mA[q]  = __ballot(prA[q]);
                mB[q]  = __ballot(prB[q]);
            }

            const int totA = (int)(__popcll(mA[0]) + __popcll(mA[1]) +
                                   __popcll(mA[2]) + __popcll(mA[3]));
            const int totB = (int)(__popcll(mB[0]) + __popcll(mB[1]) +
                                   __popcll(mB[2]) + __popcll(mB[3]));
            int basep = 0;
            if (lane == 0) basep = atomicAdd(cptr, totA | (totB << 16));
            basep = __shfl(basep, 0, 64);     // convergent broadcast

            int offA = basep & 0xffff;
            int offB = (basep >> 16) & 0xffff;
#pragma unroll
            for (int q = 0; q < 4; ++q) {
                if (prA[q]) {
                    const float d  = sqrtf(sqA[q]);
                    const float x  = d * 0.4f;    // d / 2.5
                    const float x3 = x * x * x;
                    const float cutv = 1.0f + x3 * (-10.0f + x * (15.0f - 6.0f * x));
                    const int idx = offA + (int)__popcll(mA[q] & lt);
                    if (idx < QCAP) {
                        qd[aA][idx] = d;
                        qm[aA][idx] = (tj[q] == 0) ? cutv : -cutv;
                    }
                }
                if (prB[q]) {
                    const float d  = sqrtf(sqB[q]);
                    const float x  = d * 0.4f;
                    const float x3 = x * x * x;
                    const float cutv = 1.0f + x3 * (-10.0f + x * (15.0f - 6.0f * x));
                    const int idx = offB + (int)__popcll(mB[q] & lt);
                    if (idx < QCAP) {
                        qd[aB][idx] = d;
                        qm[aB][idx] = (tj[q] == 0) ? cutv : -cutv;
                    }
                }
                offA += (int)__popcll(mA[q]); // wave-uniform prefix
                offB += (int)__popcll(mB[q]);
            }
        }
    }
    __syncthreads();
    int n[4];
    {
        const int pk01 = cnt01, pk23 = cnt23;
        n[0] = pk01 & 0xffff;  n[1] = (pk01 >> 16) & 0xffff;
        n[2] = pk23 & 0xffff;  n[3] = (pk23 >> 16) & 0xffff;
#pragma unroll
        for (int a = 0; a < 4; ++a) if (n[a] > QCAP) n[a] = QCAP;
    }
    int nmax = n[0];
    if (n[1] > nmax) nmax = n[1];
    if (n[2] > nmax) nmax = n[2];
    if (n[3] > nmax) nmax = n[3];

    // ---------- phase 1b: r-parallel RBF accumulation, 4 atoms ----------
    {
        const int slot = tid >> 4;            // pair slot 0..15
        const int r    = tid & 15;            // RBF center 0..15
        const float c  = (float)r * (2.5f / 15.0f);

        float a0[4] = {0.f, 0.f, 0.f, 0.f};   // species0, atoms 0..3
        float a1[4] = {0.f, 0.f, 0.f, 0.f};   // species1, atoms 0..3
        for (int e = slot; e < nmax; e += 16) {
#pragma unroll
            for (int a = 0; a < 4; ++a) {
                if (e < n[a]) {
                    const float d    = qd[a][e];
                    const float mm   = qm[a][e];
                    const float diff = d - c;
                    const float ex   = __expf(-(diff * diff) * 36.0f);
                    a0[a] = fmaf(fmaxf( mm, 0.0f), ex, a0[a]);
                    a1[a] = fmaf(fmaxf(-mm, 0.0f), ex, a1[a]);
                }
            }
        }
#pragma unroll
        for (int a = 0; a < 4; ++a) {
            a0[a] += __shfl_xor(a0[a], 16, 64);  a0[a] += __shfl_xor(a0[a], 32, 64);
            a1[a] += __shfl_xor(a1[a], 16, 64);  a1[a] += __shfl_xor(a1[a], 32, 64);
        }
        if (lane < 16) {
            // partial[wav][f][atom], f=2r+s -> two float4 per lane
            const float4 v0 = {a0[0], a0[1], a0[2], a0[3]};   // f = 2r
            const float4 v1 = {a1[0], a1[1], a1[2], a1[3]};   // f = 2r+1
            *(float4*)&partial[wav * 128 + r * 8]     = v0;
            *(float4*)&partial[wav * 128 + r * 8 + 4] = v1;
        }
        if (tid == 0) {
#pragma unroll
            for (int a = 0; a < 4; ++a) {
                const int t = typb[i0 + a];
                feats[a]     = (t == 0) ? 1.0f : 0.0f;   // k=0 (species0)
                feats[4 + a] = (t == 1) ? 1.0f : 0.0f;   // k=1 (species1)
            }
        }
    }
    __syncthreads();

    // ---------- wave-0-only tail: finalize feats + 3-layer MLP, 4 atoms ----------
    if (tid < HIDDEN) {
        if (tid < 32) {
            float4 acc      = *(const float4*)&partial[tid * 4];
            const float4 q1 = *(const float4*)&partial[128 + tid * 4];
            const float4 q2 = *(const float4*)&partial[256 + tid * 4];
            const float4 q3 = *(const float4*)&partial[384 + tid * 4];
            acc.x += q1.x + q2.x + q3.x;
            acc.y += q1.y + q2.y + q3.y;
            acc.z += q1.z + q2.z + q3.z;
            acc.w += q1.w + q2.w + q3.w;
            *(float4*)&feats[8 + tid * 4] = acc;     // k = 2 + f
        }
        __builtin_amdgcn_wave_barrier();

        float h[4];
        {
            const float bb = b1[tid];
            h[0] = bb; h[1] = bb; h[2] = bb; h[3] = bb;
#pragma unroll
            for (int k = 0; k < 34; ++k) {
                const float w  = W1[k * HIDDEN + tid];
                const float4 f = *(const float4*)&feats[k * 4];
                h[0] = fmaf(f.x, w, h[0]);  h[1] = fmaf(f.y, w, h[1]);
                h[2] = fmaf(f.z, w, h[2]);  h[3] = fmaf(f.w, w, h[3]);
            }
#pragma unroll
            for (int a = 0; a < 4; ++a) h[a] = h[a] / (1.0f + __expf(-h[a]));
            *(float4*)&h1s[tid * 4] = make_float4(h[0], h[1], h[2], h[3]);
        }
        __builtin_amdgcn_wave_barrier();

        {
            const float bb = b2[tid];
            h[0] = bb; h[1] = bb; h[2] = bb; h[3] = bb;
#pragma unroll
            for (int k = 0; k < HIDDEN; ++k) {
                const float w  = W2[k * HIDDEN + tid];
                const float4 f = *(const float4*)&h1s[k * 4];
                h[0] = fmaf(f.x, w, h[0]);  h[1] = fmaf(f.y, w, h[1]);
                h[2] = fmaf(f.z, w, h[2]);  h[3] = fmaf(f.w, w, h[3]);
            }
#pragma unroll
            for (int a = 0; a < 4; ++a) h[a] = h[a] / (1.0f + __expf(-h[a]));
            *(float4*)&h2s[tid * 4] = make_float4(h[0], h[1], h[2], h[3]);
        }
        __builtin_amdgcn_wave_barrier();

        {
            const float bb = b3[tid];
            float o[4] = {bb, bb, bb, bb};
#pragma unroll
            for (int k = 0; k < HIDDEN; ++k) {
                const float w  = W3[k * HIDDEN + tid];
                const float4 f = *(const float4*)&h2s[k * 4];
                o[0] = fmaf(f.x, w, o[0]);  o[1] = fmaf(f.y, w, o[1]);
                o[2] = fmaf(f.z, w, o[2]);  o[3] = fmaf(f.w, w, o[3]);
            }
            const size_t row0 = (size_t)(bidx * N_ATOMS + i0) * HIDDEN;
#pragma unroll
            for (int a = 0; a < 4; ++a)
                out[row0 + (size_t)a * HIDDEN + tid] = o[a];  // contiguous rows
        }
    }
}

extern "C" void kernel_launch(void* const* d_in, const int* in_sizes, int n_in,
                              void* d_out, int out_size, void* d_ws, size_t ws_size,
                              hipStream_t stream) {
    const float* pos   = (const float*)d_in[0];
    const int*   types = (const int*)d_in[1];
    const float* W1    = (const float*)d_in[2];
    const float* b1    = (const float*)d_in[3];
    const float* W2    = (const float*)d_in[4];
    const float* b2    = (const float*)d_in[5];
    const float* W3    = (const float*)d_in[6];
    const float* b3    = (const float*)d_in[7];
    float*       out   = (float*)d_out;

    const int BN = in_sizes[1];           // B*N = 8192
    const int nblocks = BN >> 2;          // one block per atom quad

    LocalFeatureEncoder_40063454937486_kernel<<<nblocks, NTHREADS, 0, stream>>>(
        pos, types, W1, b1, W2, b2, W3, b3, out);
}